// Round 1
// baseline (95.519 us; speedup 1.0000x reference)
//
#include <hip/hip_runtime.h>
#include <math.h>

#define B_ 4096
#define D_ 256
#define C_ 64
#define BD (B_*D_)

__device__ __forceinline__ float wave_reduce_sum(float v) {
    #pragma unroll
    for (int off = 1; off < 64; off <<= 1) v += __shfl_xor(v, off);
    return v;
}

// ---- per-block L1 partials of |W|: 1024 blocks, each 4096 floats of W ----
__global__ __launch_bounds__(256) void k_wstats(const float* __restrict__ W,
                                                float* __restrict__ l1p) {
    const float4* w4 = (const float4*)(W + (size_t)blockIdx.x * 4096);
    float s = 0.f;
    #pragma unroll
    for (int j = 0; j < 4; ++j) {
        float4 v = w4[threadIdx.x + 256 * j];
        s += fabsf(v.x) + fabsf(v.y) + fabsf(v.z) + fabsf(v.w);
    }
    s = wave_reduce_sum(s);
    __shared__ float part[4];
    int wid = threadIdx.x >> 6, lane = threadIdx.x & 63;
    if (lane == 0) part[wid] = s;
    __syncthreads();
    if (threadIdx.x == 0) l1p[blockIdx.x] = (part[0] + part[1]) + (part[2] + part[3]);
}

// ---- x: copy to out tail + per-block sum of squares ----
__global__ __launch_bounds__(256) void k_xstats(const float* __restrict__ x,
                                                float* __restrict__ out,
                                                float* __restrict__ xsqp) {
    int i = blockIdx.x * 256 + threadIdx.x;      // float4 index, 262144 total
    float4 v = ((const float4*)x)[i];
    float2* dst = (float2*)(out + BD + 2);       // 8B-aligned region
    dst[2 * i]     = make_float2(v.x, v.y);
    dst[2 * i + 1] = make_float2(v.z, v.w);
    float s = v.x * v.x + v.y * v.y + v.z * v.z + v.w * v.w;
    s = wave_reduce_sum(s);
    __shared__ float part[4];
    int wid = threadIdx.x >> 6, lane = threadIdx.x & 63;
    if (lane == 0) part[wid] = s;
    __syncthreads();
    if (threadIdx.x == 0) xsqp[blockIdx.x] = (part[0] + part[1]) + (part[2] + part[3]);
}

// ---- histogram of condition indices ----
__global__ __launch_bounds__(256) void k_hist(const int* __restrict__ c,
                                              int* __restrict__ counts) {
    int i = blockIdx.x * 256 + threadIdx.x;
    atomicAdd(&counts[c[i]], 1);
}

// ---- single block: prefix scan, mask_norm, embed_norm ----
__global__ __launch_bounds__(256) void k_setup(const int* __restrict__ counts,
                                               int* __restrict__ offsets,
                                               int* __restrict__ cursor,
                                               const float* __restrict__ l1p,
                                               const float* __restrict__ xsqp,
                                               float* __restrict__ out) {
    int tid = threadIdx.x;
    if (tid == 0) {
        int acc = 0;
        for (int cc = 0; cc < C_; ++cc) {
            offsets[cc] = acc; cursor[cc] = acc; acc += counts[cc];
        }
    }
    if (tid < 64) {
        float l1 = 0.f;
        #pragma unroll
        for (int j = 0; j < 16; ++j) l1 += l1p[tid * 16 + j];
        float mv = l1 * (float)counts[tid];
        mv = wave_reduce_sum(mv);
        if (tid == 0) out[BD] = mv;                    // mask_norm
    }
    float s = 0.f;
    #pragma unroll
    for (int j = 0; j < 4; ++j) s += xsqp[tid * 4 + j];
    s = wave_reduce_sum(s);
    __shared__ float part[4];
    int wid = tid >> 6, lane = tid & 63;
    if (lane == 0) part[wid] = s;
    __syncthreads();
    if (tid == 0) out[BD + 1] = sqrtf((part[0] + part[1]) + (part[2] + part[3]));  // embed_norm
}

// ---- scatter sample ids into per-condition buckets ----
__global__ __launch_bounds__(256) void k_scatter(const int* __restrict__ c,
                                                 int* __restrict__ cursor,
                                                 int* __restrict__ order) {
    int i = blockIdx.x * 256 + threadIdx.x;
    int pos = atomicAdd(&cursor[c[i]], 1);
    order[pos] = i;
}

// ---- grouped matvec: grid = 64 conds x 4 out-tiles, W strip in registers ----
__global__ __launch_bounds__(256) void k_matvec(const float* __restrict__ W,
                                                const float* __restrict__ b,
                                                const float* __restrict__ x,
                                                const int* __restrict__ order,
                                                const int* __restrict__ offsets,
                                                const int* __restrict__ counts,
                                                float* __restrict__ out) {
    int bid = blockIdx.x;
    int cond = bid >> 2, ot = bid & 3;
    int tid = threadIdx.x;
    int r = tid >> 2, q = tid & 3;          // 64 rows x 4 k-quarters
    int row = ot * 64 + r;
    const float4* wp = (const float4*)(W + (size_t)cond * (D_ * D_) + (size_t)row * D_ + q * 64);
    float4 Wreg[16];
    #pragma unroll
    for (int j = 0; j < 16; ++j) Wreg[j] = wp[j];
    float bias = b[cond * D_ + row];

    __shared__ float4 xs[8 * 64];           // 8 samples x 256 floats
    int start = offsets[cond], n = counts[cond];
    for (int s0 = 0; s0 < n; s0 += 8) {
        int ns = min(8, n - s0);
        __syncthreads();
        for (int u = tid; u < ns * 64; u += 256) {
            int sg = order[start + s0 + (u >> 6)];
            xs[u] = ((const float4*)x)[(size_t)sg * 64 + (u & 63)];
        }
        __syncthreads();
        for (int si = 0; si < ns; ++si) {
            float ax = 0.f, ay = 0.f, az = 0.f, aw = 0.f;
            #pragma unroll
            for (int j = 0; j < 16; ++j) {
                float4 xv = xs[si * 64 + q * 16 + j];
                ax += Wreg[j].x * xv.x;
                ay += Wreg[j].y * xv.y;
                az += Wreg[j].z * xv.z;
                aw += Wreg[j].w * xv.w;
            }
            float acc = (ax + ay) + (az + aw);
            acc += __shfl_xor(acc, 1);
            acc += __shfl_xor(acc, 2);
            if (q == 0) {
                int sg = order[start + s0 + si];
                out[(size_t)sg * D_ + row] = acc + bias;
            }
        }
    }
}

// ---- in-place row L2-normalize of out[0 .. B*D) ----
__global__ __launch_bounds__(256) void k_normalize(float* __restrict__ out) {
    int rowv = blockIdx.x * 4 + (threadIdx.x >> 6);   // 4096 rows, wave per row
    int lane = threadIdx.x & 63;
    float4* p = (float4*)out + (size_t)rowv * 64 + lane;
    float4 v = *p;
    float s = v.x * v.x + v.y * v.y + v.z * v.z + v.w * v.w;
    s = wave_reduce_sum(s);
    float inv = 1.0f / fmaxf(sqrtf(s), 1e-10f);
    v.x *= inv; v.y *= inv; v.z *= inv; v.w *= inv;
    *p = v;
}

extern "C" void kernel_launch(void* const* d_in, const int* in_sizes, int n_in,
                              void* d_out, int out_size, void* d_ws, size_t ws_size,
                              hipStream_t stream) {
    const float* x = (const float*)d_in[0];
    const float* W = (const float*)d_in[1];
    const float* b = (const float*)d_in[2];
    const int*   c = (const int*)d_in[3];
    float* out = (float*)d_out;

    int* counts  = (int*)d_ws;           // 64
    int* cursor  = counts + 64;          // 64
    int* offsets = cursor + 64;          // 64
    int* order   = offsets + 64;         // 4096
    float* l1p   = (float*)(order + B_); // 1024
    float* xsqp  = l1p + 1024;           // 1024

    hipMemsetAsync(counts, 0, 64 * sizeof(int), stream);
    k_wstats<<<1024, 256, 0, stream>>>(W, l1p);
    k_xstats<<<1024, 256, 0, stream>>>(x, out, xsqp);
    k_hist<<<16, 256, 0, stream>>>(c, counts);
    k_setup<<<1, 256, 0, stream>>>(counts, offsets, cursor, l1p, xsqp, out);
    k_scatter<<<16, 256, 0, stream>>>(c, cursor, order);
    k_matvec<<<256, 256, 0, stream>>>(W, b, x, order, offsets, counts, out);
    k_normalize<<<1024, 256, 0, stream>>>(out);
}

// Round 2
// 47.627 us; speedup vs baseline: 2.0056x; 2.0056x over previous
//
#include <hip/hip_runtime.h>
#include <math.h>

#define B_ 4096
#define D_ 256
#define C_ 64
#define BD (B_*D_)

__device__ __forceinline__ float wave_reduce_sum(float v) {
    #pragma unroll
    for (int off = 1; off < 64; off <<= 1) v += __shfl_xor(v, off);
    return v;
}

// ---- x: copy to out tail + per-block sum of squares + (first 16 blocks) histogram ----
__global__ __launch_bounds__(256) void k_xstats(const float* __restrict__ x,
                                                const int* __restrict__ c,
                                                float* __restrict__ out,
                                                float* __restrict__ xsqp,
                                                int* __restrict__ counts) {
    int i = blockIdx.x * 256 + threadIdx.x;      // float4 index, 262144 total
    float4 v = ((const float4*)x)[i];
    float2* dst = (float2*)(out + BD + 2);       // 8B-aligned region
    dst[2 * i]     = make_float2(v.x, v.y);
    dst[2 * i + 1] = make_float2(v.z, v.w);
    float s = v.x * v.x + v.y * v.y + v.z * v.z + v.w * v.w;
    s = wave_reduce_sum(s);
    __shared__ float part[4];
    int wid = threadIdx.x >> 6, lane = threadIdx.x & 63;
    if (lane == 0) part[wid] = s;
    __syncthreads();
    if (threadIdx.x == 0) xsqp[blockIdx.x] = (part[0] + part[1]) + (part[2] + part[3]);
    if (blockIdx.x < 16) atomicAdd(&counts[c[blockIdx.x * 256 + threadIdx.x]], 1);
}

// ---- single block: prefix scan, embed_norm, bucket scatter ----
__global__ __launch_bounds__(256) void k_setup(const int* __restrict__ counts,
                                               int* __restrict__ offsets,
                                               const float* __restrict__ xsqp,
                                               const int* __restrict__ c,
                                               int* __restrict__ order,
                                               float* __restrict__ out) {
    __shared__ int cur[C_];
    __shared__ float part[4];
    int tid = threadIdx.x;
    if (tid == 0) {
        int acc = 0;
        for (int cc = 0; cc < C_; ++cc) {
            offsets[cc] = acc; cur[cc] = acc; acc += counts[cc];
        }
    }
    // embed_norm from xstats partials
    float s = 0.f;
    #pragma unroll
    for (int j = 0; j < 4; ++j) s += xsqp[tid * 4 + j];
    s = wave_reduce_sum(s);
    int wid = tid >> 6, lane = tid & 63;
    if (lane == 0) part[wid] = s;
    // prefetch condition indices for scatter
    int cv[16];
    #pragma unroll
    for (int t = 0; t < 16; ++t) cv[t] = c[tid + t * 256];
    __syncthreads();
    if (tid == 0) out[BD + 1] = sqrtf((part[0] + part[1]) + (part[2] + part[3]));
    #pragma unroll
    for (int t = 0; t < 16; ++t) {
        int pos = atomicAdd(&cur[cv[t]], 1);
        order[pos] = tid + t * 256;
    }
}

// ---- grouped matvec: 64 conds x 4 row-tiles x 4 sample-slices ----
// slice-0 blocks additionally emit per-(cond,row-tile) L1(|W|) partials.
__global__ __launch_bounds__(256) void k_matvec(const float* __restrict__ W,
                                                const float* __restrict__ b,
                                                const float* __restrict__ x,
                                                const int* __restrict__ order,
                                                const int* __restrict__ offsets,
                                                const int* __restrict__ counts,
                                                float* __restrict__ out,
                                                float* __restrict__ l1p) {
    int hw = blockIdx.x;
    int bid = (hw & 7) * 128 + (hw >> 3);   // XCD swizzle: 128 consecutive logical blocks per XCD
    int cond = bid >> 4;
    int ot = (bid >> 2) & 3;
    int sl = bid & 3;
    int tid = threadIdx.x;
    int r = tid >> 2, q = tid & 3;          // 64 rows x 4 k-quarters
    int row = ot * 64 + r;

    const float4* wp = (const float4*)(W + (size_t)cond * (D_ * D_) + (size_t)row * D_ + q * 64);
    float4 Wreg[16];
    #pragma unroll
    for (int j = 0; j < 16; ++j) Wreg[j] = wp[j];
    // pin W strip in VGPRs — compiler must not re-sink the loads into the sample loop
    #pragma unroll
    for (int j = 0; j < 16; ++j)
        asm volatile("" : "+v"(Wreg[j].x), "+v"(Wreg[j].y), "+v"(Wreg[j].z), "+v"(Wreg[j].w));

    __shared__ float part[4];
    if (sl == 0) {                           // |W| L1 partial (W read exactly once overall)
        float a = 0.f;
        #pragma unroll
        for (int j = 0; j < 16; ++j)
            a += fabsf(Wreg[j].x) + fabsf(Wreg[j].y) + fabsf(Wreg[j].z) + fabsf(Wreg[j].w);
        a = wave_reduce_sum(a);
        int wid = tid >> 6, lane = tid & 63;
        if (lane == 0) part[wid] = a;
        __syncthreads();
        if (tid == 0) l1p[cond * 4 + ot] = (part[0] + part[1]) + (part[2] + part[3]);
    }

    float bias = b[cond * D_ + row];
    int start = offsets[cond], n = counts[cond];
    int per = (n + 3) >> 2;
    int s_beg = min(sl * per, n);
    int s_end = min(s_beg + per, n);

    __shared__ float4 xs[8 * 68];            // 8 samples x 4 quarters (stride 17 -> conflict-free)
    for (int s0 = s_beg; s0 < s_end; s0 += 8) {
        int ns = min(8, s_end - s0);
        __syncthreads();
        for (int u = tid; u < ns * 64; u += 256) {
            int si = u >> 6, v = u & 63;
            int sg = order[start + s0 + si];
            xs[si * 68 + (v >> 4) * 17 + (v & 15)] = ((const float4*)x)[(size_t)sg * 64 + v];
        }
        __syncthreads();
        for (int si = 0; si < ns; ++si) {
            const float4* xp = &xs[si * 68 + q * 17];
            float ax = 0.f, ay = 0.f, az = 0.f, aw = 0.f;
            #pragma unroll
            for (int j = 0; j < 16; ++j) {
                float4 xv = xp[j];
                ax += Wreg[j].x * xv.x;
                ay += Wreg[j].y * xv.y;
                az += Wreg[j].z * xv.z;
                aw += Wreg[j].w * xv.w;
            }
            float acc = (ax + ay) + (az + aw);
            acc += __shfl_xor(acc, 1);
            acc += __shfl_xor(acc, 2);
            if (q == 0) {
                int sg = order[start + s0 + si];
                out[(size_t)sg * D_ + row] = acc + bias;
            }
        }
    }
}

// ---- in-place row L2-normalize; extra block finalizes mask_norm ----
__global__ __launch_bounds__(256) void k_normalize(float* __restrict__ out,
                                                   const float* __restrict__ l1p,
                                                   const int* __restrict__ counts) {
    if (blockIdx.x == 1024) {
        int tid = threadIdx.x;
        if (tid < 64) {
            float l1 = (l1p[tid * 4 + 0] + l1p[tid * 4 + 1]) + (l1p[tid * 4 + 2] + l1p[tid * 4 + 3]);
            float mv = l1 * (float)counts[tid];
            mv = wave_reduce_sum(mv);
            if (tid == 0) out[BD] = mv;      // mask_norm
        }
        return;
    }
    int rowv = blockIdx.x * 4 + (threadIdx.x >> 6);   // 4096 rows, wave per row
    int lane = threadIdx.x & 63;
    float4* p = (float4*)out + (size_t)rowv * 64 + lane;
    float4 v = *p;
    float s = v.x * v.x + v.y * v.y + v.z * v.z + v.w * v.w;
    s = wave_reduce_sum(s);
    float inv = 1.0f / fmaxf(sqrtf(s), 1e-10f);
    v.x *= inv; v.y *= inv; v.z *= inv; v.w *= inv;
    *p = v;
}

extern "C" void kernel_launch(void* const* d_in, const int* in_sizes, int n_in,
                              void* d_out, int out_size, void* d_ws, size_t ws_size,
                              hipStream_t stream) {
    const float* x = (const float*)d_in[0];
    const float* W = (const float*)d_in[1];
    const float* b = (const float*)d_in[2];
    const int*   c = (const int*)d_in[3];
    float* out = (float*)d_out;

    int* counts  = (int*)d_ws;            // 64
    int* offsets = counts + 64;           // 64
    int* order   = offsets + 64;          // 4096
    float* xsqp  = (float*)(order + B_);  // 1024
    float* l1p   = xsqp + 1024;           // 256

    hipMemsetAsync(counts, 0, 64 * sizeof(int), stream);
    k_xstats<<<1024, 256, 0, stream>>>(x, c, out, xsqp, counts);
    k_setup<<<1, 256, 0, stream>>>(counts, offsets, xsqp, c, order, out);
    k_matvec<<<1024, 256, 0, stream>>>(W, b, x, order, offsets, counts, out, l1p);
    k_normalize<<<1025, 256, 0, stream>>>(out, l1p, counts);
}

// Round 3
// 41.338 us; speedup vs baseline: 2.3107x; 1.1522x over previous
//
#include <hip/hip_runtime.h>
#include <math.h>

#define B_ 4096
#define D_ 256
#define C_ 64
#define BD (B_*D_)

__device__ __forceinline__ float wave_reduce_sum(float v) {
    #pragma unroll
    for (int off = 1; off < 64; off <<= 1) v += __shfl_xor(v, off);
    return v;
}

// ---- x: copy to out tail + per-block sum of squares ----
__global__ __launch_bounds__(256) void k_xstats(const float* __restrict__ x,
                                                float* __restrict__ out,
                                                float* __restrict__ xsqp) {
    int i = blockIdx.x * 256 + threadIdx.x;      // float4 index, 262144 total
    float4 v = ((const float4*)x)[i];
    float2* dst = (float2*)(out + BD + 2);       // 8B-aligned region
    dst[2 * i]     = make_float2(v.x, v.y);
    dst[2 * i + 1] = make_float2(v.z, v.w);
    float s = v.x * v.x + v.y * v.y + v.z * v.z + v.w * v.w;
    s = wave_reduce_sum(s);
    __shared__ float part[4];
    int wid = threadIdx.x >> 6, lane = threadIdx.x & 63;
    if (lane == 0) part[wid] = s;
    __syncthreads();
    if (threadIdx.x == 0) xsqp[blockIdx.x] = (part[0] + part[1]) + (part[2] + part[3]);
}

// ---- single block: histogram, prefix scan, scatter, embed_norm ----
__global__ __launch_bounds__(256) void k_setup(const int* __restrict__ c,
                                               const float* __restrict__ xsqp,
                                               int* __restrict__ offsets,
                                               int* __restrict__ counts,
                                               int* __restrict__ order,
                                               float* __restrict__ out) {
    __shared__ int hist[C_];
    __shared__ int base[C_];
    __shared__ float part[4];
    int tid = threadIdx.x;
    if (tid < C_) hist[tid] = 0;
    int cv[16];
    #pragma unroll
    for (int t = 0; t < 16; ++t) cv[t] = c[tid + t * 256];
    // embed_norm from xstats partials
    float s = 0.f;
    #pragma unroll
    for (int j = 0; j < 4; ++j) s += xsqp[tid * 4 + j];
    s = wave_reduce_sum(s);
    int wid = tid >> 6, lane = tid & 63;
    if (lane == 0) part[wid] = s;
    __syncthreads();
    #pragma unroll
    for (int t = 0; t < 16; ++t) atomicAdd(&hist[cv[t]], 1);
    __syncthreads();
    if (tid == 0) {
        out[BD + 1] = sqrtf((part[0] + part[1]) + (part[2] + part[3]));
        int acc = 0;
        for (int cc = 0; cc < C_; ++cc) {
            base[cc] = acc; offsets[cc] = acc; counts[cc] = hist[cc]; acc += hist[cc];
        }
    }
    __syncthreads();
    #pragma unroll
    for (int t = 0; t < 16; ++t) {
        int pos = atomicAdd(&base[cv[t]], 1);
        order[pos] = tid + t * 256;
    }
}

// ---- grouped matvec: 64 conds x 4 row-tiles x 4 sample-slices ----
// thread = (rowgroup rg of 4 rows, k-segment kseg of 16 k); W strip 4x16 in regs.
// slice-0 blocks additionally emit per-(cond,row-tile) L1(|W|) partials.
__global__ __launch_bounds__(256) void k_matvec(const float* __restrict__ W,
                                                const float* __restrict__ b,
                                                const float* __restrict__ x,
                                                const int* __restrict__ order,
                                                const int* __restrict__ offsets,
                                                const int* __restrict__ counts,
                                                float* __restrict__ out,
                                                float* __restrict__ l1p) {
    int hw = blockIdx.x;
    int bid = (hw & 7) * 128 + (hw >> 3);   // XCD swizzle: 128 consecutive logical blocks per XCD
    int cond = bid >> 4;
    int ot = (bid >> 2) & 3;
    int sl = bid & 3;
    int tid = threadIdx.x;
    int rg = tid >> 4, kseg = tid & 15;
    int swz = kseg >> 1;                    // LDS bank swizzle shift
    int row0 = ot * 64 + rg * 4;

    float4 Wreg[4][4];                      // [row][k-float4]
    #pragma unroll
    for (int rr = 0; rr < 4; ++rr) {
        const float4* wp = (const float4*)(W + (size_t)cond * (D_ * D_) + (size_t)(row0 + rr) * D_ + kseg * 16);
        #pragma unroll
        for (int j = 0; j < 4; ++j) Wreg[rr][j] = wp[j];
    }
    #pragma unroll
    for (int rr = 0; rr < 4; ++rr)
        #pragma unroll
        for (int j = 0; j < 4; ++j)
            asm volatile("" : "+v"(Wreg[rr][j].x), "+v"(Wreg[rr][j].y), "+v"(Wreg[rr][j].z), "+v"(Wreg[rr][j].w));

    __shared__ float part[4];
    if (sl == 0) {                          // |W| L1 partial (W read exactly once overall)
        float a = 0.f;
        #pragma unroll
        for (int rr = 0; rr < 4; ++rr)
            #pragma unroll
            for (int j = 0; j < 4; ++j)
                a += fabsf(Wreg[rr][j].x) + fabsf(Wreg[rr][j].y) + fabsf(Wreg[rr][j].z) + fabsf(Wreg[rr][j].w);
        a = wave_reduce_sum(a);
        int wid = tid >> 6, lane = tid & 63;
        if (lane == 0) part[wid] = a;
        __syncthreads();
        if (tid == 0) l1p[cond * 4 + ot] = (part[0] + part[1]) + (part[2] + part[3]);
    }

    float4 bias = ((const float4*)(b + cond * D_ + ot * 64))[rg];
    int start = offsets[cond], n = counts[cond];
    int per = (n + 3) >> 2;
    int s_beg = min(sl * per, n);
    int s_end = min(s_beg + per, n);

    __shared__ float4 xs[16 * 64];          // 16 samples x 64 float4 (swizzled within kseg)
    __shared__ int sid[16];
    for (int s0 = s_beg; s0 < s_end; s0 += 16) {
        int ns = min(16, s_end - s0);
        __syncthreads();
        for (int u = tid; u < ns * 64; u += 256) {
            int si = u >> 6, v = u & 63;
            int sg = order[start + s0 + si];
            if (v == 0) sid[si] = sg;
            xs[si * 64 + (v & 0x3C) + (((v & 3) + (v >> 3)) & 3)] = ((const float4*)x)[(size_t)sg * 64 + v];
        }
        __syncthreads();
        for (int si = 0; si < ns; ++si) {
            const float4* xp = &xs[si * 64 + kseg * 4];
            float4 a0 = make_float4(0.f, 0.f, 0.f, 0.f);
            float4 a1 = a0, a2 = a0, a3 = a0;
            #pragma unroll
            for (int jl = 0; jl < 4; ++jl) {
                float4 xv = xp[(jl + swz) & 3];
                a0.x += Wreg[0][jl].x * xv.x; a0.y += Wreg[0][jl].y * xv.y;
                a0.z += Wreg[0][jl].z * xv.z; a0.w += Wreg[0][jl].w * xv.w;
                a1.x += Wreg[1][jl].x * xv.x; a1.y += Wreg[1][jl].y * xv.y;
                a1.z += Wreg[1][jl].z * xv.z; a1.w += Wreg[1][jl].w * xv.w;
                a2.x += Wreg[2][jl].x * xv.x; a2.y += Wreg[2][jl].y * xv.y;
                a2.z += Wreg[2][jl].z * xv.z; a2.w += Wreg[2][jl].w * xv.w;
                a3.x += Wreg[3][jl].x * xv.x; a3.y += Wreg[3][jl].y * xv.y;
                a3.z += Wreg[3][jl].z * xv.z; a3.w += Wreg[3][jl].w * xv.w;
            }
            float r0 = (a0.x + a0.y) + (a0.z + a0.w);
            float r1 = (a1.x + a1.y) + (a1.z + a1.w);
            float r2 = (a2.x + a2.y) + (a2.z + a2.w);
            float r3 = (a3.x + a3.y) + (a3.z + a3.w);
            #pragma unroll
            for (int off = 1; off < 16; off <<= 1) {
                r0 += __shfl_xor(r0, off);
                r1 += __shfl_xor(r1, off);
                r2 += __shfl_xor(r2, off);
                r3 += __shfl_xor(r3, off);
            }
            if (kseg == 0) {
                int sg = sid[si];
                ((float4*)out)[(size_t)sg * 64 + ot * 16 + rg] =
                    make_float4(r0 + bias.x, r1 + bias.y, r2 + bias.z, r3 + bias.w);
            }
        }
    }
}

// ---- in-place row L2-normalize; extra block finalizes mask_norm ----
__global__ __launch_bounds__(256) void k_normalize(float* __restrict__ out,
                                                   const float* __restrict__ l1p,
                                                   const int* __restrict__ counts) {
    if (blockIdx.x == 1024) {
        int tid = threadIdx.x;
        if (tid < 64) {
            float l1 = (l1p[tid * 4 + 0] + l1p[tid * 4 + 1]) + (l1p[tid * 4 + 2] + l1p[tid * 4 + 3]);
            float mv = l1 * (float)counts[tid];
            mv = wave_reduce_sum(mv);
            if (tid == 0) out[BD] = mv;      // mask_norm
        }
        return;
    }
    int rowv = blockIdx.x * 4 + (threadIdx.x >> 6);   // 4096 rows, wave per row
    int lane = threadIdx.x & 63;
    float4* p = (float4*)out + (size_t)rowv * 64 + lane;
    float4 v = *p;
    float s = v.x * v.x + v.y * v.y + v.z * v.z + v.w * v.w;
    s = wave_reduce_sum(s);
    float inv = 1.0f / fmaxf(sqrtf(s), 1e-10f);
    v.x *= inv; v.y *= inv; v.z *= inv; v.w *= inv;
    *p = v;
}

extern "C" void kernel_launch(void* const* d_in, const int* in_sizes, int n_in,
                              void* d_out, int out_size, void* d_ws, size_t ws_size,
                              hipStream_t stream) {
    const float* x = (const float*)d_in[0];
    const float* W = (const float*)d_in[1];
    const float* b = (const float*)d_in[2];
    const int*   c = (const int*)d_in[3];
    float* out = (float*)d_out;

    int* counts  = (int*)d_ws;            // 64
    int* offsets = counts + 64;           // 64
    int* order   = offsets + 64;          // 4096
    float* xsqp  = (float*)(order + B_);  // 1024
    float* l1p   = xsqp + 1024;           // 256

    k_xstats<<<1024, 256, 0, stream>>>(x, out, xsqp);
    k_setup<<<1, 256, 0, stream>>>(c, xsqp, offsets, counts, order, out);
    k_matvec<<<1024, 256, 0, stream>>>(W, b, x, order, offsets, counts, out, l1p);
    k_normalize<<<1025, 256, 0, stream>>>(out, l1p, counts);
}

// Round 4
// 33.746 us; speedup vs baseline: 2.8305x; 1.2250x over previous
//
#include <hip/hip_runtime.h>
#include <math.h>

#define B_ 4096
#define D_ 256
#define C_ 64
#define BD (B_*D_)

__device__ __forceinline__ float wave_reduce_sum(float v) {
    #pragma unroll
    for (int off = 1; off < 64; off <<= 1) v += __shfl_xor(v, off);
    return v;
}

// full sum across each aligned 16-lane group, result in all 16 lanes.
// VALU-only (DPP row_ror), keeps the DS pipe free.
__device__ __forceinline__ float dpp_sum16(float v) {
    int t;
    t = __builtin_amdgcn_update_dpp(0, __float_as_int(v), 0x121, 0xF, 0xF, true); v += __int_as_float(t); // ror:1
    t = __builtin_amdgcn_update_dpp(0, __float_as_int(v), 0x122, 0xF, 0xF, true); v += __int_as_float(t); // ror:2
    t = __builtin_amdgcn_update_dpp(0, __float_as_int(v), 0x124, 0xF, 0xF, true); v += __int_as_float(t); // ror:4
    t = __builtin_amdgcn_update_dpp(0, __float_as_int(v), 0x128, 0xF, 0xF, true); v += __int_as_float(t); // ror:8
    return v;
}

// ---- blocks 0..1023: x copy to out tail + per-block sum of squares ----
// ---- block 1024: histogram + prefix scan + bucket scatter (needs only c) ----
__global__ __launch_bounds__(256) void k_prep(const float* __restrict__ x,
                                              const int* __restrict__ c,
                                              float* __restrict__ out,
                                              float* __restrict__ xsqp,
                                              int* __restrict__ offsets,
                                              int* __restrict__ counts,
                                              int* __restrict__ order) {
    int tid = threadIdx.x;
    if (blockIdx.x == 1024) {
        __shared__ int hist[C_];
        __shared__ int base[C_];
        if (tid < C_) hist[tid] = 0;
        int cv[16];
        #pragma unroll
        for (int t = 0; t < 16; ++t) cv[t] = c[tid + t * 256];
        __syncthreads();
        #pragma unroll
        for (int t = 0; t < 16; ++t) atomicAdd(&hist[cv[t]], 1);
        __syncthreads();
        if (tid == 0) {
            int acc = 0;
            for (int cc = 0; cc < C_; ++cc) {
                base[cc] = acc; offsets[cc] = acc; counts[cc] = hist[cc]; acc += hist[cc];
            }
        }
        __syncthreads();
        #pragma unroll
        for (int t = 0; t < 16; ++t) {
            int pos = atomicAdd(&base[cv[t]], 1);
            order[pos] = tid + t * 256;
        }
        return;
    }
    int i = blockIdx.x * 256 + tid;              // float4 index, 262144 total
    float4 v = ((const float4*)x)[i];
    float2* dst = (float2*)(out + BD + 2);       // 8B-aligned region
    dst[2 * i]     = make_float2(v.x, v.y);
    dst[2 * i + 1] = make_float2(v.z, v.w);
    float s = v.x * v.x + v.y * v.y + v.z * v.z + v.w * v.w;
    s = wave_reduce_sum(s);
    __shared__ float part[4];
    int wid = tid >> 6, lane = tid & 63;
    if (lane == 0) part[wid] = s;
    __syncthreads();
    if (tid == 0) xsqp[blockIdx.x] = (part[0] + part[1]) + (part[2] + part[3]);
}

// ---- grouped matvec: 64 conds x 4 row-tiles x 4 sample-slices ----
// thread = (rowgroup rg of 4 rows, k-segment kseg of 16 k); W strip 4x16 in regs.
// 16-lane reduction done with DPP (VALU) instead of shfl (DS pipe).
__global__ __launch_bounds__(256) void k_matvec(const float* __restrict__ W,
                                                const float* __restrict__ b,
                                                const float* __restrict__ x,
                                                const int* __restrict__ order,
                                                const int* __restrict__ offsets,
                                                const int* __restrict__ counts,
                                                float* __restrict__ out,
                                                float* __restrict__ l1p) {
    int hw = blockIdx.x;
    int bid = (hw & 7) * 128 + (hw >> 3);   // XCD swizzle: 128 consecutive logical blocks per XCD
    int cond = bid >> 4;
    int ot = (bid >> 2) & 3;
    int sl = bid & 3;
    int tid = threadIdx.x;
    int rg = tid >> 4, kseg = tid & 15;
    int swz = kseg >> 1;                    // LDS bank swizzle shift
    int row0 = ot * 64 + rg * 4;

    float4 Wreg[4][4];                      // [row][k-float4]
    #pragma unroll
    for (int rr = 0; rr < 4; ++rr) {
        const float4* wp = (const float4*)(W + (size_t)cond * (D_ * D_) + (size_t)(row0 + rr) * D_ + kseg * 16);
        #pragma unroll
        for (int j = 0; j < 4; ++j) Wreg[rr][j] = wp[j];
    }
    #pragma unroll
    for (int rr = 0; rr < 4; ++rr)
        #pragma unroll
        for (int j = 0; j < 4; ++j)
            asm volatile("" : "+v"(Wreg[rr][j].x), "+v"(Wreg[rr][j].y), "+v"(Wreg[rr][j].z), "+v"(Wreg[rr][j].w));

    __shared__ float part[4];
    if (sl == 0) {                          // |W| L1 partial (W read exactly once overall)
        float a = 0.f;
        #pragma unroll
        for (int rr = 0; rr < 4; ++rr)
            #pragma unroll
            for (int j = 0; j < 4; ++j)
                a += fabsf(Wreg[rr][j].x) + fabsf(Wreg[rr][j].y) + fabsf(Wreg[rr][j].z) + fabsf(Wreg[rr][j].w);
        a = wave_reduce_sum(a);
        int wid = tid >> 6, lane = tid & 63;
        if (lane == 0) part[wid] = a;
        __syncthreads();
        if (tid == 0) l1p[cond * 4 + ot] = (part[0] + part[1]) + (part[2] + part[3]);
    }

    float4 bias = ((const float4*)(b + cond * D_ + ot * 64))[rg];
    int start = offsets[cond], n = counts[cond];
    int per = (n + 3) >> 2;
    int s_beg = min(sl * per, n);
    int s_end = min(s_beg + per, n);

    __shared__ float4 xs[16 * 64];          // 16 samples x 64 float4 (swizzled within kseg)
    __shared__ int sid[16];
    for (int s0 = s_beg; s0 < s_end; s0 += 16) {
        int ns = min(16, s_end - s0);
        __syncthreads();
        for (int u = tid; u < ns * 64; u += 256) {
            int si = u >> 6, v = u & 63;
            int sg = order[start + s0 + si];
            if (v == 0) sid[si] = sg;
            xs[si * 64 + (v & 0x3C) + (((v & 3) + (v >> 3)) & 3)] = ((const float4*)x)[(size_t)sg * 64 + v];
        }
        __syncthreads();
        for (int si = 0; si < ns; ++si) {
            const float4* xp = &xs[si * 64 + kseg * 4];
            float4 a0 = make_float4(0.f, 0.f, 0.f, 0.f);
            float4 a1 = a0, a2 = a0, a3 = a0;
            #pragma unroll
            for (int jl = 0; jl < 4; ++jl) {
                float4 xv = xp[(jl + swz) & 3];
                a0.x += Wreg[0][jl].x * xv.x; a0.y += Wreg[0][jl].y * xv.y;
                a0.z += Wreg[0][jl].z * xv.z; a0.w += Wreg[0][jl].w * xv.w;
                a1.x += Wreg[1][jl].x * xv.x; a1.y += Wreg[1][jl].y * xv.y;
                a1.z += Wreg[1][jl].z * xv.z; a1.w += Wreg[1][jl].w * xv.w;
                a2.x += Wreg[2][jl].x * xv.x; a2.y += Wreg[2][jl].y * xv.y;
                a2.z += Wreg[2][jl].z * xv.z; a2.w += Wreg[2][jl].w * xv.w;
                a3.x += Wreg[3][jl].x * xv.x; a3.y += Wreg[3][jl].y * xv.y;
                a3.z += Wreg[3][jl].z * xv.z; a3.w += Wreg[3][jl].w * xv.w;
            }
            float r0 = dpp_sum16((a0.x + a0.y) + (a0.z + a0.w));
            float r1 = dpp_sum16((a1.x + a1.y) + (a1.z + a1.w));
            float r2 = dpp_sum16((a2.x + a2.y) + (a2.z + a2.w));
            float r3 = dpp_sum16((a3.x + a3.y) + (a3.z + a3.w));
            if (kseg == 0) {
                int sg = sid[si];
                ((float4*)out)[(size_t)sg * 64 + ot * 16 + rg] =
                    make_float4(r0 + bias.x, r1 + bias.y, r2 + bias.z, r3 + bias.w);
            }
        }
    }
}

// ---- blocks 0..1023: in-place row L2-normalize ----
// ---- block 1024: finalize embed_norm (xsqp) and mask_norm (l1p, counts) ----
__global__ __launch_bounds__(256) void k_finish(float* __restrict__ out,
                                                const float* __restrict__ xsqp,
                                                const float* __restrict__ l1p,
                                                const int* __restrict__ counts) {
    int tid = threadIdx.x;
    if (blockIdx.x == 1024) {
        __shared__ float part[4];
        float s = 0.f;
        #pragma unroll
        for (int j = 0; j < 4; ++j) s += xsqp[tid * 4 + j];
        s = wave_reduce_sum(s);
        int wid = tid >> 6, lane = tid & 63;
        if (lane == 0) part[wid] = s;
        __syncthreads();
        if (tid < 64) {
            float l1 = (l1p[tid * 4 + 0] + l1p[tid * 4 + 1]) + (l1p[tid * 4 + 2] + l1p[tid * 4 + 3]);
            float mv = l1 * (float)counts[tid];
            mv = wave_reduce_sum(mv);
            if (tid == 0) out[BD] = mv;                                              // mask_norm
        }
        if (tid == 0) out[BD + 1] = sqrtf((part[0] + part[1]) + (part[2] + part[3])); // embed_norm
        return;
    }
    int rowv = blockIdx.x * 4 + (tid >> 6);   // 4096 rows, wave per row
    int lane = tid & 63;
    float4* p = (float4*)out + (size_t)rowv * 64 + lane;
    float4 v = *p;
    float s = v.x * v.x + v.y * v.y + v.z * v.z + v.w * v.w;
    s = wave_reduce_sum(s);
    float inv = 1.0f / fmaxf(sqrtf(s), 1e-10f);
    v.x *= inv; v.y *= inv; v.z *= inv; v.w *= inv;
    *p = v;
}

extern "C" void kernel_launch(void* const* d_in, const int* in_sizes, int n_in,
                              void* d_out, int out_size, void* d_ws, size_t ws_size,
                              hipStream_t stream) {
    const float* x = (const float*)d_in[0];
    const float* W = (const float*)d_in[1];
    const float* b = (const float*)d_in[2];
    const int*   c = (const int*)d_in[3];
    float* out = (float*)d_out;

    int* counts  = (int*)d_ws;            // 64
    int* offsets = counts + 64;           // 64
    int* order   = offsets + 64;          // 4096
    float* xsqp  = (float*)(order + B_);  // 1024
    float* l1p   = xsqp + 1024;           // 256

    k_prep<<<1025, 256, 0, stream>>>(x, c, out, xsqp, offsets, counts, order);
    k_matvec<<<1024, 256, 0, stream>>>(W, b, x, order, offsets, counts, out, l1p);
    k_finish<<<1025, 256, 0, stream>>>(out, xsqp, l1p, counts);
}

// Round 5
// 28.762 us; speedup vs baseline: 3.3210x; 1.1733x over previous
//
#include <hip/hip_runtime.h>
#include <math.h>

#define B_ 4096
#define D_ 256
#define C_ 64
#define BD (B_*D_)

__device__ __forceinline__ float wave_reduce_sum(float v) {
    #pragma unroll
    for (int off = 1; off < 64; off <<= 1) v += __shfl_xor(v, off);
    return v;
}

// full sum across each aligned 16-lane group, result in all 16 lanes (VALU-only DPP)
__device__ __forceinline__ float dpp_sum16(float v) {
    int t;
    t = __builtin_amdgcn_update_dpp(0, __float_as_int(v), 0x121, 0xF, 0xF, true); v += __int_as_float(t); // ror:1
    t = __builtin_amdgcn_update_dpp(0, __float_as_int(v), 0x122, 0xF, 0xF, true); v += __int_as_float(t); // ror:2
    t = __builtin_amdgcn_update_dpp(0, __float_as_int(v), 0x124, 0xF, 0xF, true); v += __int_as_float(t); // ror:4
    t = __builtin_amdgcn_update_dpp(0, __float_as_int(v), 0x128, 0xF, 0xF, true); v += __int_as_float(t); // ror:8
    return v;
}

// ---- fused: per-block x-copy stripe + Sum(x^2) partial, local bucket scan,
//      W-L1 partial (sl==0), grouped matvec.  grid = 64 conds x 4 ot x 4 sl ----
__global__ __launch_bounds__(256) void k_main(const float* __restrict__ W,
                                              const float* __restrict__ b,
                                              const float* __restrict__ x,
                                              const int* __restrict__ c,
                                              float* __restrict__ out,
                                              float* __restrict__ l1p,
                                              float* __restrict__ xsqp,
                                              int* __restrict__ cnt4) {
    int hw = blockIdx.x;
    int bid = (hw & 7) * 128 + (hw >> 3);   // XCD swizzle: 128 consecutive logical blocks per XCD
    int cond = bid >> 4;
    int ot = (bid >> 2) & 3;
    int sl = bid & 3;
    int tid = threadIdx.x;
    int rg = tid >> 4, kseg = tid & 15;
    int swz = kseg >> 1;
    int row0 = ot * 64 + rg * 4;

    // --- issue independent loads early: W strip, x-copy stripe, c scan ---
    float4 Wreg[4][4];
    #pragma unroll
    for (int rr = 0; rr < 4; ++rr) {
        const float4* wp = (const float4*)(W + (size_t)cond * (D_ * D_) + (size_t)(row0 + rr) * D_ + kseg * 16);
        #pragma unroll
        for (int j = 0; j < 4; ++j) Wreg[rr][j] = wp[j];
    }
    int xi = bid * 256 + tid;                       // float4 index into x (262144 total / 1024 blocks)
    float4 xv = ((const float4*)x)[xi];
    int4 cv[4];
    #pragma unroll
    for (int t = 0; t < 4; ++t) cv[t] = ((const int4*)c)[tid + 256 * t];

    #pragma unroll
    for (int rr = 0; rr < 4; ++rr)
        #pragma unroll
        for (int j = 0; j < 4; ++j)
            asm volatile("" : "+v"(Wreg[rr][j].x), "+v"(Wreg[rr][j].y), "+v"(Wreg[rr][j].z), "+v"(Wreg[rr][j].w));

    __shared__ float part_x[4];
    __shared__ float part_w[4];
    __shared__ int slist[1024];
    __shared__ int nlist;
    if (tid == 0) nlist = 0;

    // x copy to out tail + sumsq partial
    float2* dst = (float2*)(out + BD + 2);
    dst[2 * xi]     = make_float2(xv.x, xv.y);
    dst[2 * xi + 1] = make_float2(xv.z, xv.w);
    float s = xv.x * xv.x + xv.y * xv.y + xv.z * xv.z + xv.w * xv.w;
    s = wave_reduce_sum(s);
    int wid = tid >> 6, lane = tid & 63;
    if (lane == 0) part_x[wid] = s;

    // |W| L1 partial (only sl==0 blocks: W counted exactly once overall)
    if (sl == 0) {
        float a = 0.f;
        #pragma unroll
        for (int rr = 0; rr < 4; ++rr)
            #pragma unroll
            for (int j = 0; j < 4; ++j)
                a += fabsf(Wreg[rr][j].x) + fabsf(Wreg[rr][j].y) + fabsf(Wreg[rr][j].z) + fabsf(Wreg[rr][j].w);
        a = wave_reduce_sum(a);
        if (lane == 0) part_w[wid] = a;
    }
    __syncthreads();
    if (tid == 0) {
        xsqp[bid] = (part_x[0] + part_x[1]) + (part_x[2] + part_x[3]);
        if (sl == 0) l1p[cond * 4 + ot] = (part_w[0] + part_w[1]) + (part_w[2] + part_w[3]);
    }

    // local bucket scan: slice sl owns samples i == sl (mod 4); int4 component sl
    #pragma unroll
    for (int t = 0; t < 4; ++t) {
        int4 q = cv[t];
        int cc = (sl == 0) ? q.x : (sl == 1) ? q.y : (sl == 2) ? q.z : q.w;
        if (cc == cond) {
            int pos = atomicAdd(&nlist, 1);
            slist[pos] = 4 * (tid + 256 * t) + sl;
        }
    }
    __syncthreads();
    int n = nlist;
    if (ot == 0 && tid == 0) cnt4[cond * 4 + sl] = n;

    float4 bias = ((const float4*)(b + cond * D_ + ot * 64))[rg];

    __shared__ float4 xs[16 * 64];
    for (int s0 = 0; s0 < n; s0 += 16) {
        int ns = min(16, n - s0);
        __syncthreads();
        for (int u = tid; u < ns * 64; u += 256) {
            int si = u >> 6, v = u & 63;
            int sg = slist[s0 + si];
            xs[si * 64 + (v & 0x3C) + (((v & 3) + (v >> 3)) & 3)] = ((const float4*)x)[(size_t)sg * 64 + v];
        }
        __syncthreads();
        for (int si = 0; si < ns; ++si) {
            const float4* xp = &xs[si * 64 + kseg * 4];
            float4 a0 = make_float4(0.f, 0.f, 0.f, 0.f);
            float4 a1 = a0, a2 = a0, a3 = a0;
            #pragma unroll
            for (int jl = 0; jl < 4; ++jl) {
                float4 q = xp[(jl + swz) & 3];
                a0.x += Wreg[0][jl].x * q.x; a0.y += Wreg[0][jl].y * q.y;
                a0.z += Wreg[0][jl].z * q.z; a0.w += Wreg[0][jl].w * q.w;
                a1.x += Wreg[1][jl].x * q.x; a1.y += Wreg[1][jl].y * q.y;
                a1.z += Wreg[1][jl].z * q.z; a1.w += Wreg[1][jl].w * q.w;
                a2.x += Wreg[2][jl].x * q.x; a2.y += Wreg[2][jl].y * q.y;
                a2.z += Wreg[2][jl].z * q.z; a2.w += Wreg[2][jl].w * q.w;
                a3.x += Wreg[3][jl].x * q.x; a3.y += Wreg[3][jl].y * q.y;
                a3.z += Wreg[3][jl].z * q.z; a3.w += Wreg[3][jl].w * q.w;
            }
            float r0 = dpp_sum16((a0.x + a0.y) + (a0.z + a0.w));
            float r1 = dpp_sum16((a1.x + a1.y) + (a1.z + a1.w));
            float r2 = dpp_sum16((a2.x + a2.y) + (a2.z + a2.w));
            float r3 = dpp_sum16((a3.x + a3.y) + (a3.z + a3.w));
            if (kseg == 0) {
                int sg = slist[s0 + si];
                ((float4*)out)[(size_t)sg * 64 + ot * 16 + rg] =
                    make_float4(r0 + bias.x, r1 + bias.y, r2 + bias.z, r3 + bias.w);
            }
        }
    }
}

// ---- blocks 0..1023: in-place row L2-normalize ----
// ---- block 1024: finalize embed_norm (xsqp) and mask_norm (l1p, cnt4) ----
__global__ __launch_bounds__(256) void k_finish(float* __restrict__ out,
                                                const float* __restrict__ xsqp,
                                                const float* __restrict__ l1p,
                                                const int* __restrict__ cnt4) {
    int tid = threadIdx.x;
    if (blockIdx.x == 1024) {
        __shared__ float part[4];
        float s = 0.f;
        #pragma unroll
        for (int j = 0; j < 4; ++j) s += xsqp[tid * 4 + j];
        s = wave_reduce_sum(s);
        int wid = tid >> 6, lane = tid & 63;
        if (lane == 0) part[wid] = s;
        __syncthreads();
        if (tid < 64) {
            float l1 = (l1p[tid * 4 + 0] + l1p[tid * 4 + 1]) + (l1p[tid * 4 + 2] + l1p[tid * 4 + 3]);
            float cnt = (float)((cnt4[tid * 4 + 0] + cnt4[tid * 4 + 1]) + (cnt4[tid * 4 + 2] + cnt4[tid * 4 + 3]));
            float mv = l1 * cnt;
            mv = wave_reduce_sum(mv);
            if (tid == 0) out[BD] = mv;                                               // mask_norm
        }
        if (tid == 0) out[BD + 1] = sqrtf((part[0] + part[1]) + (part[2] + part[3])); // embed_norm
        return;
    }
    int rowv = blockIdx.x * 4 + (tid >> 6);   // 4096 rows, wave per row
    int lane = tid & 63;
    float4* p = (float4*)out + (size_t)rowv * 64 + lane;
    float4 v = *p;
    float s = v.x * v.x + v.y * v.y + v.z * v.z + v.w * v.w;
    s = wave_reduce_sum(s);
    float inv = 1.0f / fmaxf(sqrtf(s), 1e-10f);
    v.x *= inv; v.y *= inv; v.z *= inv; v.w *= inv;
    *p = v;
}

extern "C" void kernel_launch(void* const* d_in, const int* in_sizes, int n_in,
                              void* d_out, int out_size, void* d_ws, size_t ws_size,
                              hipStream_t stream) {
    const float* x = (const float*)d_in[0];
    const float* W = (const float*)d_in[1];
    const float* b = (const float*)d_in[2];
    const int*   c = (const int*)d_in[3];
    float* out = (float*)d_out;

    float* xsqp = (float*)d_ws;           // 1024
    float* l1p  = xsqp + 1024;            // 256
    int*   cnt4 = (int*)(l1p + 256);      // 256

    k_main<<<1024, 256, 0, stream>>>(W, b, x, c, out, l1p, xsqp, cnt4);
    k_finish<<<1025, 256, 0, stream>>>(out, xsqp, l1p, cnt4);
}